// Round 4
// baseline (788.623 us; speedup 1.0000x reference)
//
#include <hip/hip_runtime.h>
#include <hip/hip_bf16.h>

typedef __bf16 bf16x8 __attribute__((ext_vector_type(8)));
typedef float f32x4 __attribute__((ext_vector_type(4)));

#define T_TOK 4096
#define H_DIM 1024
#define F_DIM 2048
#define NEXP 8
#define TOTROWS 8192   // T_TOK * TOP_K, always exact (top-2 distinct experts)
#define MAXTILES 80

__device__ inline unsigned short f2b(float f) {
    unsigned int u = __float_as_uint(f);
    unsigned int r = (u + 0x7fffu + ((u >> 16) & 1u)) >> 16;
    return (unsigned short)r;
}

// ---------------- router: logits -> softmax -> top2 -> renorm (4 tokens/block) ----------------
__global__ __launch_bounds__(256) void router_kernel(const float* __restrict__ x,
                                                     const float* __restrict__ gw,
                                                     int* __restrict__ sel, float* __restrict__ selw,
                                                     int* __restrict__ cnt) {
    int t = blockIdx.x * 4 + (threadIdx.x >> 6);
    int lane = threadIdx.x & 63;
    float acc[8] = {0.f,0.f,0.f,0.f,0.f,0.f,0.f,0.f};
    const float* xr = x + (size_t)t * H_DIM;
    for (int h = lane; h < H_DIM; h += 64) {
        float xv = xr[h];
        const float4* g = (const float4*)(gw + h * 8);
        float4 g0 = g[0], g1 = g[1];
        acc[0] += xv * g0.x; acc[1] += xv * g0.y; acc[2] += xv * g0.z; acc[3] += xv * g0.w;
        acc[4] += xv * g1.x; acc[5] += xv * g1.y; acc[6] += xv * g1.z; acc[7] += xv * g1.w;
    }
#pragma unroll
    for (int off = 32; off >= 1; off >>= 1)
#pragma unroll
        for (int e = 0; e < 8; ++e)
            acc[e] += __shfl_down(acc[e], off);
    if (lane == 0) {
        float mx = acc[0];
#pragma unroll
        for (int e = 1; e < 8; ++e) mx = fmaxf(mx, acc[e]);
        float p[8]; float s = 0.f;
#pragma unroll
        for (int e = 0; e < 8; ++e) { p[e] = expf(acc[e] - mx); s += p[e]; }
        float inv_s = 1.f / s;
#pragma unroll
        for (int e = 0; e < 8; ++e) p[e] *= inv_s;
        int e1 = 0; float p1 = p[0];
#pragma unroll
        for (int e = 1; e < 8; ++e) if (p[e] > p1) { p1 = p[e]; e1 = e; }
        int e2 = -1; float p2 = -1.f;
#pragma unroll
        for (int e = 0; e < 8; ++e) { if (e == e1) continue; if (p[e] > p2) { p2 = p[e]; e2 = e; } }
        float inv = 1.f / (p1 + p2);
        sel[t * 2 + 0] = e1; sel[t * 2 + 1] = e2;
        selw[t * 2 + 0] = p1 * inv; selw[t * 2 + 1] = p2 * inv;
        atomicAdd(&cnt[e1], 1); atomicAdd(&cnt[e2], 1);
    }
}

// ---------------- prefix scan + tile table ----------------
__global__ void scan_kernel(const int* __restrict__ cnt, int* __restrict__ off,
                            int* __restrict__ tileExp, int* __restrict__ tileM0) {
    if (blockIdx.x == 0 && threadIdx.x == 0) {
        int o = 0;
        for (int e = 0; e < NEXP; ++e) { off[e] = o; o += cnt[e]; }
        int nt = 0;
        for (int e = 0; e < NEXP; ++e)
            for (int m0 = 0; m0 < cnt[e]; m0 += 128) { tileExp[nt] = e; tileM0[nt] = m0; nt++; }
        for (int i = nt; i < MAXTILES; ++i) { tileExp[i] = -1; tileM0[i] = 0; }
    }
}

// ---------------- scatter: build compacted row lists + token->row map ----------------
__global__ __launch_bounds__(256) void scatter_kernel(const int* __restrict__ sel,
                                                      const float* __restrict__ selw,
                                                      const int* __restrict__ off,
                                                      int* __restrict__ fill,
                                                      int* __restrict__ rowTok, float* __restrict__ rowWgt,
                                                      int* __restrict__ tokRow) {
    int t = blockIdx.x * 256 + threadIdx.x;
    if (t >= T_TOK) return;
#pragma unroll
    for (int k = 0; k < 2; ++k) {
        int e = sel[t * 2 + k];
        int slot = atomicAdd(&fill[e], 1);
        int r = off[e] + slot;
        rowTok[r] = t;
        rowWgt[r] = selw[t * 2 + k];
        tokRow[t * 2 + k] = r;
    }
}

// ---------------- gather: x rows (fp32) -> Xg (bf16), compacted order ----------------
__global__ __launch_bounds__(256) void gather_kernel(const float* __restrict__ x,
                                                     const int* __restrict__ rowTok,
                                                     unsigned short* __restrict__ Xg) {
    int r = blockIdx.x;
    int t = rowTok[r];
    const float4* src = (const float4*)(x + (size_t)t * H_DIM);
    int i = threadIdx.x;
    float4 v = src[i];
    ushort4 o;
    o.x = f2b(v.x); o.y = f2b(v.y); o.z = f2b(v.z); o.w = f2b(v.w);
    ((ushort4*)(Xg + (size_t)r * H_DIM))[i] = o;
}

// ---------------- fused transpose+cvt for all 3 weight tensors ----------------
__global__ __launch_bounds__(256) void transpose_cvt_kernel(
        const float* __restrict__ w_up, const float* __restrict__ w_gate,
        const float* __restrict__ w_down,
        unsigned short* __restrict__ wTu, unsigned short* __restrict__ wTg,
        unsigned short* __restrict__ wTd) {
    __shared__ unsigned short lt[64 * 68];
    int z = blockIdx.z;
    int e = blockIdx.y;
    const float* src; unsigned short* dst; int R, C, tr, tc;
    if (z == 0)      { src = w_up;   dst = wTu; R = H_DIM; C = F_DIM; }
    else if (z == 1) { src = w_gate; dst = wTg; R = H_DIM; C = F_DIM; }
    else             { src = w_down; dst = wTd; R = F_DIM; C = H_DIM; }
    if (R == H_DIM) { tc = blockIdx.x & 31; tr = blockIdx.x >> 5; }
    else            { tc = blockIdx.x & 15; tr = blockIdx.x >> 4; }
    const float* s = src + (size_t)e * H_DIM * F_DIM;
    unsigned short* d = dst + (size_t)e * H_DIM * F_DIM;
    int r0 = tr * 64, c0 = tc * 64;
    int tid = threadIdx.x;
    int fc = tid & 15, row = tid >> 4;
#pragma unroll
    for (int i = 0; i < 4; ++i) {
        int r = row + i * 16;
        float4 v = *(const float4*)(s + (size_t)(r0 + r) * C + c0 + fc * 4);
        lt[(fc * 4 + 0) * 68 + r] = f2b(v.x);
        lt[(fc * 4 + 1) * 68 + r] = f2b(v.y);
        lt[(fc * 4 + 2) * 68 + r] = f2b(v.z);
        lt[(fc * 4 + 3) * 68 + r] = f2b(v.w);
    }
    __syncthreads();
    int ch = tid & 7, cc = tid >> 3;
#pragma unroll
    for (int i = 0; i < 2; ++i) {
        int c = cc + i * 32;
        uint2 lo = *(const uint2*)&lt[c * 68 + ch * 8];
        uint2 hi = *(const uint2*)&lt[c * 68 + ch * 8 + 4];
        uint4 o = make_uint4(lo.x, lo.y, hi.x, hi.y);
        *(uint4*)(d + (size_t)(c0 + c) * R + r0 + ch * 8) = o;
    }
}

// ---------------- fused up/gate GEMM, flatmm: register-direct, no LDS, no barriers ----------------
__global__ __launch_bounds__(256, 2) void gemm_upgate_kernel(
        const unsigned short* __restrict__ Xg,
        const unsigned short* __restrict__ wTu,   // [E][F][H] (k-major)
        const unsigned short* __restrict__ wTg,
        unsigned short* __restrict__ inner,       // [TOTROWS][F]
        const int* __restrict__ tileExp, const int* __restrict__ tileM0,
        const int* __restrict__ off, const int* __restrict__ cnt) {
    int bt = blockIdx.y;
    int e = tileExp[bt];
    if (e < 0) return;
    int m0 = tileM0[bt];
    int r0 = off[e] + m0;
    int valid = cnt[e] - m0;
    int f0 = blockIdx.x * 128;
    const unsigned short* bu = wTu + (size_t)e * F_DIM * H_DIM + (size_t)f0 * H_DIM;
    const unsigned short* bg = wTg + (size_t)e * F_DIM * H_DIM + (size_t)f0 * H_DIM;
    int tid = threadIdx.x;
    int lane = tid & 63, wid = tid >> 6;
    int wm = wid >> 1, wn = wid & 1;
    int l16 = lane & 15, quad = lane >> 4;

    int aOff[4], bOff[4];
#pragma unroll
    for (int i = 0; i < 4; ++i) {
        int row = r0 + wm * 64 + i * 16 + l16;
        if (row > TOTROWS - 1) row = TOTROWS - 1;   // clamp tail: stay in Xg
        aOff[i] = row * H_DIM + quad * 8;
        bOff[i] = (wn * 64 + i * 16 + l16) * H_DIM + quad * 8;
    }

    f32x4 accU[4][4], accG[4][4];
#pragma unroll
    for (int i = 0; i < 4; ++i)
#pragma unroll
        for (int j = 0; j < 4; ++j) { accU[i][j] = (f32x4)0.f; accG[i][j] = (f32x4)0.f; }

    bf16x8 a0[4], u0[4], g0[4];
#pragma unroll
    for (int i = 0; i < 4; ++i) {
        a0[i] = *(const bf16x8*)(Xg + aOff[i]);
        u0[i] = *(const bf16x8*)(bu + bOff[i]);
        g0[i] = *(const bf16x8*)(bg + bOff[i]);
    }
#pragma unroll 1
    for (int k0 = 0; k0 < H_DIM; k0 += 64) {
        bf16x8 a1[4], u1[4], g1[4];
#pragma unroll
        for (int i = 0; i < 4; ++i) {
            a1[i] = *(const bf16x8*)(Xg + aOff[i] + k0 + 32);
            u1[i] = *(const bf16x8*)(bu + bOff[i] + k0 + 32);
            g1[i] = *(const bf16x8*)(bg + bOff[i] + k0 + 32);
        }
#pragma unroll
        for (int i = 0; i < 4; ++i)
#pragma unroll
            for (int j = 0; j < 4; ++j) {
                accU[i][j] = __builtin_amdgcn_mfma_f32_16x16x32_bf16(a0[i], u0[j], accU[i][j], 0, 0, 0);
                accG[i][j] = __builtin_amdgcn_mfma_f32_16x16x32_bf16(a0[i], g0[j], accG[i][j], 0, 0, 0);
            }
#pragma unroll
        for (int i = 0; i < 4; ++i) {
            a0[i] = *(const bf16x8*)(Xg + aOff[i] + k0 + 64);   // last iter: dead overread, in-ws
            u0[i] = *(const bf16x8*)(bu + bOff[i] + k0 + 64);
            g0[i] = *(const bf16x8*)(bg + bOff[i] + k0 + 64);
        }
#pragma unroll
        for (int i = 0; i < 4; ++i)
#pragma unroll
            for (int j = 0; j < 4; ++j) {
                accU[i][j] = __builtin_amdgcn_mfma_f32_16x16x32_bf16(a1[i], u1[j], accU[i][j], 0, 0, 0);
                accG[i][j] = __builtin_amdgcn_mfma_f32_16x16x32_bf16(a1[i], g1[j], accG[i][j], 0, 0, 0);
            }
    }
#pragma unroll
    for (int i = 0; i < 4; ++i) {
#pragma unroll
        for (int rr = 0; rr < 4; ++rr) {
            int ml = wm * 64 + i * 16 + quad * 4 + rr;
            if (ml >= valid) continue;
            size_t base = (size_t)(r0 + ml) * F_DIM + f0;
#pragma unroll
            for (int j = 0; j < 4; ++j) {
                float u = accU[i][j][rr];
                float g = accG[i][j][rr];
                float v = u / (1.f + expf(-u)) * g;   // silu(up) * gate
                inner[base + wn * 64 + j * 16 + l16] = f2b(v);
            }
        }
    }
}

// ---------------- down GEMM, flatmm -> scaled fp32 partial rows ----------------
__global__ __launch_bounds__(256, 3) void gemm_down_kernel(
        const unsigned short* __restrict__ inner,  // [TOTROWS][F]
        const unsigned short* __restrict__ wTd,    // [E][H][F] (k-major)
        float* __restrict__ part,                  // [TOTROWS][H]
        const int* __restrict__ tileExp, const int* __restrict__ tileM0,
        const int* __restrict__ off, const int* __restrict__ cnt,
        const float* __restrict__ rowWgt) {
    int bt = blockIdx.y;
    int e = tileExp[bt];
    if (e < 0) return;
    int m0 = tileM0[bt];
    int r0 = off[e] + m0;
    int valid = cnt[e] - m0;
    int h0 = blockIdx.x * 128;
    const unsigned short* bp = wTd + (size_t)e * H_DIM * F_DIM + (size_t)h0 * F_DIM;
    int tid = threadIdx.x;
    int lane = tid & 63, wid = tid >> 6;
    int wm = wid >> 1, wn = wid & 1;
    int l16 = lane & 15, quad = lane >> 4;

    int aOff[4], bOff[4];
#pragma unroll
    for (int i = 0; i < 4; ++i) {
        int row = r0 + wm * 64 + i * 16 + l16;
        if (row > TOTROWS - 1) row = TOTROWS - 1;   // clamp tail: stay in inner
        aOff[i] = row * F_DIM + quad * 8;
        bOff[i] = (wn * 64 + i * 16 + l16) * F_DIM + quad * 8;
    }

    f32x4 acc[4][4];
#pragma unroll
    for (int i = 0; i < 4; ++i)
#pragma unroll
        for (int j = 0; j < 4; ++j) acc[i][j] = (f32x4)0.f;

    bf16x8 a0[4], b0[4];
#pragma unroll
    for (int i = 0; i < 4; ++i) {
        a0[i] = *(const bf16x8*)(inner + aOff[i]);
        b0[i] = *(const bf16x8*)(bp + bOff[i]);
    }
#pragma unroll 1
    for (int k0 = 0; k0 < F_DIM; k0 += 64) {
        bf16x8 a1[4], b1[4];
#pragma unroll
        for (int i = 0; i < 4; ++i) {
            a1[i] = *(const bf16x8*)(inner + aOff[i] + k0 + 32);
            b1[i] = *(const bf16x8*)(bp + bOff[i] + k0 + 32);
        }
#pragma unroll
        for (int i = 0; i < 4; ++i)
#pragma unroll
            for (int j = 0; j < 4; ++j)
                acc[i][j] = __builtin_amdgcn_mfma_f32_16x16x32_bf16(a0[i], b0[j], acc[i][j], 0, 0, 0);
#pragma unroll
        for (int i = 0; i < 4; ++i) {
            a0[i] = *(const bf16x8*)(inner + aOff[i] + k0 + 64);
            b0[i] = *(const bf16x8*)(bp + bOff[i] + k0 + 64);
        }
#pragma unroll
        for (int i = 0; i < 4; ++i)
#pragma unroll
            for (int j = 0; j < 4; ++j)
                acc[i][j] = __builtin_amdgcn_mfma_f32_16x16x32_bf16(a1[i], b1[j], acc[i][j], 0, 0, 0);
    }
#pragma unroll
    for (int i = 0; i < 4; ++i) {
#pragma unroll
        for (int rr = 0; rr < 4; ++rr) {
            int ml = wm * 64 + i * 16 + quad * 4 + rr;
            if (ml >= valid) continue;
            int gr = r0 + ml;
            float w = rowWgt[gr];
            float* orow = part + (size_t)gr * H_DIM + h0;
#pragma unroll
            for (int j = 0; j < 4; ++j)
                orow[wn * 64 + j * 16 + l16] = w * acc[i][j][rr];
        }
    }
}

// ---------------- combine: out[t] = part[r1] + part[r2] ----------------
__global__ __launch_bounds__(256) void combine_kernel(const float* __restrict__ part,
                                                      const int* __restrict__ tokRow,
                                                      float* __restrict__ out) {
    int t = blockIdx.x;
    int r1 = tokRow[t * 2 + 0], r2 = tokRow[t * 2 + 1];
    int i = threadIdx.x;
    float4 a = ((const float4*)(part + (size_t)r1 * H_DIM))[i];
    float4 b = ((const float4*)(part + (size_t)r2 * H_DIM))[i];
    float4 o;
    o.x = a.x + b.x; o.y = a.y + b.y; o.z = a.z + b.z; o.w = a.w + b.w;
    ((float4*)(out + (size_t)t * H_DIM))[i] = o;
}

extern "C" void kernel_launch(void* const* d_in, const int* in_sizes, int n_in,
                              void* d_out, int out_size, void* d_ws, size_t ws_size,
                              hipStream_t stream) {
    const float* x      = (const float*)d_in[0];
    const float* gw     = (const float*)d_in[1];
    const float* w_up   = (const float*)d_in[2];
    const float* w_gate = (const float*)d_in[3];
    const float* w_down = (const float*)d_in[4];
    float* out = (float*)d_out;

    char* ws = (char*)d_ws;
    size_t o = 0;
    unsigned short* wTu = (unsigned short*)(ws + o); o += (size_t)NEXP * F_DIM * H_DIM * 2;
    unsigned short* wTg = (unsigned short*)(ws + o); o += (size_t)NEXP * F_DIM * H_DIM * 2;
    unsigned short* wTd = (unsigned short*)(ws + o); o += (size_t)NEXP * H_DIM * F_DIM * 2;
    unsigned short* Xg  = (unsigned short*)(ws + o); o += (size_t)TOTROWS * H_DIM * 2;
    unsigned short* inner = (unsigned short*)(ws + o); o += (size_t)TOTROWS * F_DIM * 2;
    o += 512 * 1024;  // pad: k-overreads past inner stay in ws
    int*   rowTok = (int*)(ws + o);   o += TOTROWS * 4;
    float* rowWgt = (float*)(ws + o); o += TOTROWS * 4;
    int*   tokRow = (int*)(ws + o);   o += T_TOK * 2 * 4;
    int*   sel    = (int*)(ws + o);   o += T_TOK * 2 * 4;
    float* selw   = (float*)(ws + o); o += T_TOK * 2 * 4;
    int*   cnt    = (int*)(ws + o);   o += 8 * 4;
    int*   fill   = (int*)(ws + o);   o += 8 * 4;
    int*   off_   = (int*)(ws + o);   o += 8 * 4;
    int*   tileExp = (int*)(ws + o);  o += MAXTILES * 4;
    int*   tileM0  = (int*)(ws + o);  o += MAXTILES * 4;
    // part[TOTROWS][H] fp32 aliases wTu+wTg (dead after gemm_upgate; stream-serial)
    float* part = (float*)wTu;

    hipMemsetAsync(cnt, 0, 16 * 4, stream);
    router_kernel<<<T_TOK / 4, 256, 0, stream>>>(x, gw, sel, selw, cnt);
    scan_kernel<<<1, 64, 0, stream>>>(cnt, off_, tileExp, tileM0);
    scatter_kernel<<<T_TOK / 256, 256, 0, stream>>>(sel, selw, off_, fill, rowTok, rowWgt, tokRow);
    gather_kernel<<<TOTROWS, 256, 0, stream>>>(x, rowTok, Xg);
    transpose_cvt_kernel<<<dim3(512, NEXP, 3), 256, 0, stream>>>(w_up, w_gate, w_down, wTu, wTg, wTd);
    gemm_upgate_kernel<<<dim3(F_DIM / 128, 72), 256, 0, stream>>>(Xg, wTu, wTg, inner, tileExp, tileM0, off_, cnt);
    gemm_down_kernel<<<dim3(H_DIM / 128, 72), 256, 0, stream>>>(inner, wTd, part, tileExp, tileM0, off_, cnt, rowWgt);
    combine_kernel<<<T_TOK, 256, 0, stream>>>(part, tokRow, out);
}

// Round 6
// 507.138 us; speedup vs baseline: 1.5550x; 1.5550x over previous
//
#include <hip/hip_runtime.h>
#include <hip/hip_bf16.h>

typedef __bf16 bf16x8 __attribute__((ext_vector_type(8)));
typedef float f32x4 __attribute__((ext_vector_type(4)));

#define T_TOK 4096
#define H_DIM 1024
#define F_DIM 2048
#define NEXP 8
#define TOTROWS 8192   // T_TOK * TOP_K, always exact (top-2 distinct experts)
#define MAXTILES 80

__device__ inline unsigned short f2b(float f) {
    unsigned int u = __float_as_uint(f);
    unsigned int r = (u + 0x7fffu + ((u >> 16) & 1u)) >> 16;
    return (unsigned short)r;
}

// async global->LDS, 16B per lane. LDS dst = wave-uniform base + lane*16.
__device__ inline void gload16(const void* g, void* l) {
    __builtin_amdgcn_global_load_lds(
        (const __attribute__((address_space(1))) unsigned int*)g,
        (__attribute__((address_space(3))) unsigned int*)l,
        16, 0, 0);
}

// ---------------- router: logits -> softmax -> top2 -> renorm (4 tokens/block, no atomics) ----
__global__ __launch_bounds__(256) void router_kernel(const float* __restrict__ x,
                                                     const float* __restrict__ gw,
                                                     int* __restrict__ sel, float* __restrict__ selw) {
    int t = blockIdx.x * 4 + (threadIdx.x >> 6);
    int lane = threadIdx.x & 63;
    float acc[8] = {0.f,0.f,0.f,0.f,0.f,0.f,0.f,0.f};
    const float* xr = x + (size_t)t * H_DIM;
    for (int h = lane; h < H_DIM; h += 64) {
        float xv = xr[h];
        const float4* g = (const float4*)(gw + h * 8);
        float4 g0 = g[0], g1 = g[1];
        acc[0] += xv * g0.x; acc[1] += xv * g0.y; acc[2] += xv * g0.z; acc[3] += xv * g0.w;
        acc[4] += xv * g1.x; acc[5] += xv * g1.y; acc[6] += xv * g1.z; acc[7] += xv * g1.w;
    }
#pragma unroll
    for (int off = 32; off >= 1; off >>= 1)
#pragma unroll
        for (int e = 0; e < 8; ++e)
            acc[e] += __shfl_down(acc[e], off);
    if (lane == 0) {
        float mx = acc[0];
#pragma unroll
        for (int e = 1; e < 8; ++e) mx = fmaxf(mx, acc[e]);
        float p[8]; float s = 0.f;
#pragma unroll
        for (int e = 0; e < 8; ++e) { p[e] = expf(acc[e] - mx); s += p[e]; }
        float inv_s = 1.f / s;
#pragma unroll
        for (int e = 0; e < 8; ++e) p[e] *= inv_s;
        int e1 = 0; float p1 = p[0];
#pragma unroll
        for (int e = 1; e < 8; ++e) if (p[e] > p1) { p1 = p[e]; e1 = e; }
        int e2 = -1; float p2 = -1.f;
#pragma unroll
        for (int e = 0; e < 8; ++e) { if (e == e1) continue; if (p[e] > p2) { p2 = p[e]; e2 = e; } }
        float inv = 1.f / (p1 + p2);
        sel[t * 2 + 0] = e1; sel[t * 2 + 1] = e2;
        selw[t * 2 + 0] = p1 * inv; selw[t * 2 + 1] = p2 * inv;
    }
}

// ---------------- scan: histogram sel -> cnt/off/fill/tile table (1 block) ----------------
__global__ __launch_bounds__(256) void scan_kernel(const int* __restrict__ sel,
                                                   int* __restrict__ cnt, int* __restrict__ off,
                                                   int* __restrict__ fill,
                                                   int* __restrict__ tileExp, int* __restrict__ tileM0) {
    __shared__ int h[NEXP];
    int tid = threadIdx.x;
    if (tid < NEXP) h[tid] = 0;
    __syncthreads();
    for (int i = tid; i < TOTROWS; i += 256) atomicAdd(&h[sel[i]], 1);
    __syncthreads();
    if (tid == 0) {
        int o = 0;
        for (int e = 0; e < NEXP; ++e) { cnt[e] = h[e]; off[e] = o; o += h[e]; fill[e] = 0; }
        int nt = 0;
        for (int e = 0; e < NEXP; ++e)
            for (int m0 = 0; m0 < h[e]; m0 += 128) { tileExp[nt] = e; tileM0[nt] = m0; nt++; }
        for (int i = nt; i < MAXTILES; ++i) { tileExp[i] = -1; tileM0[i] = 0; }
    }
}

// ---------------- fused scatter+gather: slots + copy x row (bf16) to both expert rows --------
__global__ __launch_bounds__(256) void scatgath_kernel(const int* __restrict__ sel,
                                                       const float* __restrict__ selw,
                                                       const int* __restrict__ off,
                                                       int* __restrict__ fill,
                                                       float* __restrict__ rowWgt,
                                                       int* __restrict__ tokRow,
                                                       const float* __restrict__ x,
                                                       unsigned short* __restrict__ Xg) {
    __shared__ int rs[2];
    int t = blockIdx.x;
    int tid = threadIdx.x;
    if (tid == 0) {
#pragma unroll
        for (int k = 0; k < 2; ++k) {
            int e = sel[t * 2 + k];
            int slot = atomicAdd(&fill[e], 1);
            int r = off[e] + slot;
            rowWgt[r] = selw[t * 2 + k];
            tokRow[t * 2 + k] = r;
            rs[k] = r;
        }
    }
    __syncthreads();
    int r1 = rs[0], r2 = rs[1];
    float4 v = ((const float4*)(x + (size_t)t * H_DIM))[tid];
    ushort4 o;
    o.x = f2b(v.x); o.y = f2b(v.y); o.z = f2b(v.z); o.w = f2b(v.w);
    ((ushort4*)(Xg + (size_t)r1 * H_DIM))[tid] = o;
    ((ushort4*)(Xg + (size_t)r2 * H_DIM))[tid] = o;
}

// ---------------- fused transpose+cvt for all 3 weight tensors ----------------
__global__ __launch_bounds__(256) void transpose_cvt_kernel(
        const float* __restrict__ w_up, const float* __restrict__ w_gate,
        const float* __restrict__ w_down,
        unsigned short* __restrict__ wTu, unsigned short* __restrict__ wTg,
        unsigned short* __restrict__ wTd) {
    __shared__ unsigned short lt[64 * 68];
    int z = blockIdx.z;
    int e = blockIdx.y;
    const float* src; unsigned short* dst; int R, C, tr, tc;
    if (z == 0)      { src = w_up;   dst = wTu; R = H_DIM; C = F_DIM; }
    else if (z == 1) { src = w_gate; dst = wTg; R = H_DIM; C = F_DIM; }
    else             { src = w_down; dst = wTd; R = F_DIM; C = H_DIM; }
    if (R == H_DIM) { tc = blockIdx.x & 31; tr = blockIdx.x >> 5; }
    else            { tc = blockIdx.x & 15; tr = blockIdx.x >> 4; }
    const float* s = src + (size_t)e * H_DIM * F_DIM;
    unsigned short* d = dst + (size_t)e * H_DIM * F_DIM;
    int r0 = tr * 64, c0 = tc * 64;
    int tid = threadIdx.x;
    int fc = tid & 15, row = tid >> 4;
#pragma unroll
    for (int i = 0; i < 4; ++i) {
        int r = row + i * 16;
        float4 v = *(const float4*)(s + (size_t)(r0 + r) * C + c0 + fc * 4);
        lt[(fc * 4 + 0) * 68 + r] = f2b(v.x);
        lt[(fc * 4 + 1) * 68 + r] = f2b(v.y);
        lt[(fc * 4 + 2) * 68 + r] = f2b(v.z);
        lt[(fc * 4 + 3) * 68 + r] = f2b(v.w);
    }
    __syncthreads();
    int ch = tid & 7, cc = tid >> 3;
#pragma unroll
    for (int i = 0; i < 2; ++i) {
        int c = cc + i * 32;
        uint2 lo = *(const uint2*)&lt[c * 68 + ch * 8];
        uint2 hi = *(const uint2*)&lt[c * 68 + ch * 8 + 4];
        uint4 o = make_uint4(lo.x, lo.y, hi.x, hi.y);
        *(uint4*)(d + (size_t)(c0 + c) * R + r0 + ch * 8) = o;
    }
}

// ---------------- fused up/gate GEMM, BK=64, swizzled global_load_lds staging ----------------
// LDS tile: [128 rows][8 chunks of 16B]; lds pos c in row r holds source chunk c^(r&7).
__global__ __launch_bounds__(256, 2) void gemm_upgate_kernel(
        const unsigned short* __restrict__ Xg,
        const unsigned short* __restrict__ wTu,   // [E][F][H] (k-major)
        const unsigned short* __restrict__ wTg,
        unsigned short* __restrict__ inner,       // [TOTROWS][F]
        const int* __restrict__ tileExp, const int* __restrict__ tileM0,
        const int* __restrict__ off, const int* __restrict__ cnt) {
    __shared__ __align__(16) unsigned short la[128 * 64];
    __shared__ __align__(16) unsigned short lbu[128 * 64];
    __shared__ __align__(16) unsigned short lbg[128 * 64];
    int bt = blockIdx.y;
    int e = tileExp[bt];
    if (e < 0) return;
    int m0 = tileM0[bt];
    int r0 = off[e] + m0;
    int valid = cnt[e] - m0;
    int f0 = blockIdx.x * 128;
    const unsigned short* aB = Xg + (size_t)r0 * H_DIM;
    const unsigned short* bu = wTu + (size_t)e * F_DIM * H_DIM + (size_t)f0 * H_DIM;
    const unsigned short* bg = wTg + (size_t)e * F_DIM * H_DIM + (size_t)f0 * H_DIM;
    int tid = threadIdx.x;
    int lane = tid & 63, wid = tid >> 6;
    int wm = wid >> 1, wn = wid & 1;
    int l16 = lane & 15, quad = lane >> 4;

    // staging: 16 wave-instrs fill 128x64; chunk = it*256+tid; row=chunk>>3; swizzled src chunk
    int srcOff[4];
#pragma unroll
    for (int it = 0; it < 4; ++it) {
        int chunk = it * 256 + tid;
        int row = chunk >> 3;
        srcOff[it] = row * H_DIM + (((chunk & 7) ^ (row & 7)) << 3);
    }
    f32x4 accU[4][4], accG[4][4];
#pragma unroll
    for (int i = 0; i < 4; ++i)
#pragma unroll
        for (int j = 0; j < 4; ++j) { accU[i][j] = (f32x4)0.f; accG[i][j] = (f32x4)0.f; }

    for (int k0 = 0; k0 < H_DIM; k0 += 64) {
        __syncthreads();
#pragma unroll
        for (int it = 0; it < 4; ++it) {
            int lbase = it * 2048 + wid * 512;   // 256 chunks/it * 16B = 2048 elems (was the R5 bug)
            gload16(aB + srcOff[it] + k0, &la[lbase]);    // tail rows overread into ws (discarded)
            gload16(bu + srcOff[it] + k0, &lbu[lbase]);
            gload16(bg + srcOff[it] + k0, &lbg[lbase]);
        }
        __syncthreads();
#pragma unroll
        for (int h = 0; h < 2; ++h) {
            bf16x8 af[4], bfu[4], bfg[4];
#pragma unroll
            for (int i = 0; i < 4; ++i) {
                int lr = wm * 64 + i * 16 + l16;
                af[i] = *(const bf16x8*)&la[lr * 64 + ((((h * 4 + quad) ^ (lr & 7))) << 3)];
            }
#pragma unroll
            for (int j = 0; j < 4; ++j) {
                int lr = wn * 64 + j * 16 + l16;
                int p = lr * 64 + ((((h * 4 + quad) ^ (lr & 7))) << 3);
                bfu[j] = *(const bf16x8*)&lbu[p];
                bfg[j] = *(const bf16x8*)&lbg[p];
            }
#pragma unroll
            for (int i = 0; i < 4; ++i)
#pragma unroll
                for (int j = 0; j < 4; ++j) {
                    accU[i][j] = __builtin_amdgcn_mfma_f32_16x16x32_bf16(af[i], bfu[j], accU[i][j], 0, 0, 0);
                    accG[i][j] = __builtin_amdgcn_mfma_f32_16x16x32_bf16(af[i], bfg[j], accG[i][j], 0, 0, 0);
                }
        }
    }
#pragma unroll
    for (int i = 0; i < 4; ++i) {
#pragma unroll
        for (int rr = 0; rr < 4; ++rr) {
            int ml = wm * 64 + i * 16 + quad * 4 + rr;
            if (ml >= valid) continue;
            size_t base = (size_t)(r0 + ml) * F_DIM + f0;
#pragma unroll
            for (int j = 0; j < 4; ++j) {
                float u = accU[i][j][rr];
                float g = accG[i][j][rr];
                float v = u / (1.f + expf(-u)) * g;   // silu(up) * gate
                inner[base + wn * 64 + j * 16 + l16] = f2b(v);
            }
        }
    }
}

// ---------------- down GEMM, BK=64 -> scaled fp32 partial rows (no atomics) ----------------
__global__ __launch_bounds__(256, 2) void gemm_down_kernel(
        const unsigned short* __restrict__ inner,  // [TOTROWS][F]
        const unsigned short* __restrict__ wTd,    // [E][H][F] (k-major)
        float* __restrict__ part,                  // [TOTROWS][H]
        const int* __restrict__ tileExp, const int* __restrict__ tileM0,
        const int* __restrict__ off, const int* __restrict__ cnt,
        const float* __restrict__ rowWgt) {
    __shared__ __align__(16) unsigned short la[128 * 64];
    __shared__ __align__(16) unsigned short lb[128 * 64];
    int bt = blockIdx.y;
    int e = tileExp[bt];
    if (e < 0) return;
    int m0 = tileM0[bt];
    int r0 = off[e] + m0;
    int valid = cnt[e] - m0;
    int h0 = blockIdx.x * 128;
    const unsigned short* aB = inner + (size_t)r0 * F_DIM;
    const unsigned short* bp = wTd + (size_t)e * H_DIM * F_DIM + (size_t)h0 * F_DIM;
    int tid = threadIdx.x;
    int lane = tid & 63, wid = tid >> 6;
    int wm = wid >> 1, wn = wid & 1;
    int l16 = lane & 15, quad = lane >> 4;

    int srcOff[4];
#pragma unroll
    for (int it = 0; it < 4; ++it) {
        int chunk = it * 256 + tid;
        int row = chunk >> 3;
        srcOff[it] = row * F_DIM + (((chunk & 7) ^ (row & 7)) << 3);
    }
    f32x4 acc[4][4];
#pragma unroll
    for (int i = 0; i < 4; ++i)
#pragma unroll
        for (int j = 0; j < 4; ++j) acc[i][j] = (f32x4)0.f;

    for (int k0 = 0; k0 < F_DIM; k0 += 64) {
        __syncthreads();
#pragma unroll
        for (int it = 0; it < 4; ++it) {
            int lbase = it * 2048 + wid * 512;   // fixed base (R5 bug)
            gload16(aB + srcOff[it] + k0, &la[lbase]);    // tail rows overread into ws pad
            gload16(bp + srcOff[it] + k0, &lb[lbase]);
        }
        __syncthreads();
#pragma unroll
        for (int h = 0; h < 2; ++h) {
            bf16x8 af[4], bf[4];
#pragma unroll
            for (int i = 0; i < 4; ++i) {
                int lr = wm * 64 + i * 16 + l16;
                af[i] = *(const bf16x8*)&la[lr * 64 + ((((h * 4 + quad) ^ (lr & 7))) << 3)];
            }
#pragma unroll
            for (int j = 0; j < 4; ++j) {
                int lr = wn * 64 + j * 16 + l16;
                bf[j] = *(const bf16x8*)&lb[lr * 64 + ((((h * 4 + quad) ^ (lr & 7))) << 3)];
            }
#pragma unroll
            for (int i = 0; i < 4; ++i)
#pragma unroll
                for (int j = 0; j < 4; ++j)
                    acc[i][j] = __builtin_amdgcn_mfma_f32_16x16x32_bf16(af[i], bf[j], acc[i][j], 0, 0, 0);
        }
    }
#pragma unroll
    for (int i = 0; i < 4; ++i) {
#pragma unroll
        for (int rr = 0; rr < 4; ++rr) {
            int ml = wm * 64 + i * 16 + quad * 4 + rr;
            if (ml >= valid) continue;
            int gr = r0 + ml;
            float w = rowWgt[gr];
            float* orow = part + (size_t)gr * H_DIM + h0;
#pragma unroll
            for (int j = 0; j < 4; ++j)
                orow[wn * 64 + j * 16 + l16] = w * acc[i][j][rr];
        }
    }
}

// ---------------- combine: out[t] = part[r1] + part[r2] ----------------
__global__ __launch_bounds__(256) void combine_kernel(const float* __restrict__ part,
                                                      const int* __restrict__ tokRow,
                                                      float* __restrict__ out) {
    int t = blockIdx.x;
    int r1 = tokRow[t * 2 + 0], r2 = tokRow[t * 2 + 1];
    int i = threadIdx.x;
    float4 a = ((const float4*)(part + (size_t)r1 * H_DIM))[i];
    float4 b = ((const float4*)(part + (size_t)r2 * H_DIM))[i];
    float4 o;
    o.x = a.x + b.x; o.y = a.y + b.y; o.z = a.z + b.z; o.w = a.w + b.w;
    ((float4*)(out + (size_t)t * H_DIM))[i] = o;
}

extern "C" void kernel_launch(void* const* d_in, const int* in_sizes, int n_in,
                              void* d_out, int out_size, void* d_ws, size_t ws_size,
                              hipStream_t stream) {
    const float* x      = (const float*)d_in[0];
    const float* gw     = (const float*)d_in[1];
    const float* w_up   = (const float*)d_in[2];
    const float* w_gate = (const float*)d_in[3];
    const float* w_down = (const float*)d_in[4];
    float* out = (float*)d_out;

    char* ws = (char*)d_ws;
    size_t o = 0;
    unsigned short* wTu = (unsigned short*)(ws + o); o += (size_t)NEXP * F_DIM * H_DIM * 2;
    unsigned short* wTg = (unsigned short*)(ws + o); o += (size_t)NEXP * F_DIM * H_DIM * 2;
    unsigned short* wTd = (unsigned short*)(ws + o); o += (size_t)NEXP * H_DIM * F_DIM * 2;
    unsigned short* Xg  = (unsigned short*)(ws + o); o += (size_t)TOTROWS * H_DIM * 2;
    unsigned short* inner = (unsigned short*)(ws + o); o += (size_t)TOTROWS * F_DIM * 2;
    o += 1024 * 1024;  // pad: tail-row overreads past inner (up to ~516KB) stay in ws
    float* rowWgt = (float*)(ws + o); o += TOTROWS * 4;
    int*   tokRow = (int*)(ws + o);   o += T_TOK * 2 * 4;
    int*   sel    = (int*)(ws + o);   o += T_TOK * 2 * 4;
    float* selw   = (float*)(ws + o); o += T_TOK * 2 * 4;
    int*   cnt    = (int*)(ws + o);   o += 8 * 4;
    int*   fill   = (int*)(ws + o);   o += 8 * 4;
    int*   off_   = (int*)(ws + o);   o += 8 * 4;
    int*   tileExp = (int*)(ws + o);  o += MAXTILES * 4;
    int*   tileM0  = (int*)(ws + o);  o += MAXTILES * 4;
    // part[TOTROWS][H] fp32 aliases wTu+wTg (dead after gemm_upgate; stream-serial)
    float* part = (float*)wTu;

    router_kernel<<<T_TOK / 4, 256, 0, stream>>>(x, gw, sel, selw);
    scan_kernel<<<1, 256, 0, stream>>>(sel, cnt, off_, fill, tileExp, tileM0);
    scatgath_kernel<<<T_TOK, 256, 0, stream>>>(sel, selw, off_, fill, rowWgt, tokRow, x, Xg);
    transpose_cvt_kernel<<<dim3(512, NEXP, 3), 256, 0, stream>>>(w_up, w_gate, w_down, wTu, wTg, wTd);
    gemm_upgate_kernel<<<dim3(F_DIM / 128, 72), 256, 0, stream>>>(Xg, wTu, wTg, inner, tileExp, tileM0, off_, cnt);
    gemm_down_kernel<<<dim3(H_DIM / 128, 72), 256, 0, stream>>>(inner, wTd, part, tileExp, tileM0, off_, cnt, rowWgt);
    combine_kernel<<<T_TOK, 256, 0, stream>>>(part, tokRow, out);
}